// Round 2
// baseline (515.138 us; speedup 1.0000x reference)
//
#include <hip/hip_runtime.h>

// out[B=16384, ONUM=512] = x[B, INUM=4096] @ wB[ONUM, INUM]^T, wB = (u < weight)
// Strategy: binarize wB -> bf16 {0,1} in d_ws (exact), cast x -> bf16 on the fly
// (absmax 8.0 vs threshold 22.56), mfma_f32_16x16x32_bf16 GEMM.
// R2: XOR-swizzle Bs chunk placement to kill the 16-way bank conflict on
//     B-fragment ds_read_b128 (row stride was exactly 32 banks).

#define M_DIM 16384
#define N_DIM 512
#define K_DIM 4096
#define BM 128
#define BN 128
#define BK 64

using bf16x8 = __attribute__((ext_vector_type(8))) short;
using f32x4  = __attribute__((ext_vector_type(4))) float;

typedef __attribute__((address_space(1))) const void glb_cv;
typedef __attribute__((address_space(3))) void lds_v;

__device__ __forceinline__ unsigned short f2bf(float f) {
    union { float f; unsigned int u; } v;
    v.f = f;
    unsigned int r = v.u + 0x7FFFu + ((v.u >> 16) & 1u);   // RNE
    return (unsigned short)(r >> 16);
}

// ---------------- binarize: wB[o,k] = (u < weight) ? 1.0bf16 : 0 ----------------
__global__ __launch_bounds__(256) void binarize_kernel(const float* __restrict__ w,
                                                       const float* __restrict__ u,
                                                       unsigned short* __restrict__ wb) {
    int i = (blockIdx.x * 256 + threadIdx.x) * 4;
    float4 wv = *(const float4*)(w + i);
    float4 uv = *(const float4*)(u + i);
    ushort4 o;
    o.x = (uv.x < wv.x) ? 0x3F80u : 0u;
    o.y = (uv.y < wv.y) ? 0x3F80u : 0u;
    o.z = (uv.z < wv.z) ? 0x3F80u : 0u;
    o.w = (uv.w < wv.w) ? 0x3F80u : 0u;
    *(ushort4*)(wb + i) = o;
}

// ---------------- GEMM: 128x128 tile, BK=64, 4 waves (2x2), 4x4 frags/wave ----------------
__global__ __launch_bounds__(256) void gemm_bin_kernel(const float* __restrict__ x,
                                                       const unsigned short* __restrict__ wb,
                                                       float* __restrict__ out) {
    __shared__ unsigned short As[BM][72];        // padded stride 144B: 4-bank row rotation, conflict-free
    __shared__ unsigned short Bs[BN * BK];       // flat; 16B chunk (r,c) lives at index r*8 + (c^(r&7))

    const int t    = threadIdx.x;
    const int lane = t & 63;
    const int wave = t >> 6;
    const int bn   = blockIdx.x;                 // N tile fastest -> x-tile LLC reuse
    const int bm   = blockIdx.y;

    const int wm = (wave & 1) * 64;
    const int wn = (wave >> 1) * 64;

    f32x4 acc[4][4] = {};

    const int arow = t >> 4;
    const int acol = (t & 15) * 4;
    const float* xg = x + (size_t)(bm * BM) * K_DIM;
    const unsigned short* wbg = wb + (size_t)(bn * BN) * K_DIM;

    for (int k0 = 0; k0 < K_DIM; k0 += BK) {
        // ---- stage A: 128x64 fp32 -> bf16 -> LDS ----
        const float* ag = xg + k0;
#pragma unroll
        for (int j = 0; j < 8; ++j) {
            int r = j * 16 + arow;
            float4 v = *(const float4*)(ag + (size_t)r * K_DIM + acol);
            ushort4 h;
            h.x = f2bf(v.x); h.y = f2bf(v.y); h.z = f2bf(v.z); h.w = f2bf(v.w);
            *(ushort4*)(&As[r][acol]) = h;
        }
        // ---- stage B via global_load_lds (16B/lane), XOR-swizzled placement ----
        // lds chunk e holds global chunk (rb = e>>3, gc = (e&7) ^ (rb&7))
#pragma unroll
        for (int c = 0; c < 4; ++c) {
            int e  = c * 256 + t;
            int rb = e >> 3;
            int gc = (e & 7) ^ (rb & 7);
            const unsigned short* gsrc = wbg + (size_t)rb * K_DIM + k0 + gc * 8;
            unsigned short* ldst = Bs + (size_t)e * 8;
            __builtin_amdgcn_global_load_lds((glb_cv*)(const void*)gsrc,
                                             (lds_v*)(void*)ldst, 16, 0, 0);
        }
        __syncthreads();

        // ---- compute: 2 k-steps of 32 ----
#pragma unroll
        for (int kk = 0; kk < 2; ++kk) {
            const int krow = kk * 32 + (lane >> 4) * 8;
            const int cc   = krow >> 3;          // chunk col 0..7
            bf16x8 af[4], bfr[4];
#pragma unroll
            for (int i = 0; i < 4; ++i)
                af[i] = *(const bf16x8*)(&As[wm + i * 16 + (lane & 15)][krow]);
#pragma unroll
            for (int i = 0; i < 4; ++i) {
                int rb = wn + i * 16 + (lane & 15);
                bfr[i] = *(const bf16x8*)(Bs + (size_t)(rb * 8 + (cc ^ (rb & 7))) * 8);
            }
#pragma unroll
            for (int i = 0; i < 4; ++i)
#pragma unroll
                for (int j = 0; j < 4; ++j)
                    acc[i][j] = __builtin_amdgcn_mfma_f32_16x16x32_bf16(af[i], bfr[j], acc[i][j], 0, 0, 0);
        }
        __syncthreads();
    }

    // ---- epilogue: C/D layout col=lane&15, row=(lane>>4)*4+reg ----
    const int col0 = bn * BN + wn + (lane & 15);
    const int row0 = bm * BM + wm + (lane >> 4) * 4;
#pragma unroll
    for (int i = 0; i < 4; ++i)
#pragma unroll
        for (int j = 0; j < 4; ++j)
#pragma unroll
            for (int r = 0; r < 4; ++r)
                out[(size_t)(row0 + i * 16 + r) * N_DIM + (col0 + j * 16)] = acc[i][j][r];
}

extern "C" void kernel_launch(void* const* d_in, const int* in_sizes, int n_in,
                              void* d_out, int out_size, void* d_ws, size_t ws_size,
                              hipStream_t stream) {
    const float* x = (const float*)d_in[0];
    const float* w = (const float*)d_in[1];
    const float* u = (const float*)d_in[2];
    float* out = (float*)d_out;
    unsigned short* wb = (unsigned short*)d_ws;   // 512*4096*2 = 4 MB

    binarize_kernel<<<dim3(N_DIM * K_DIM / 4 / 256), dim3(256), 0, stream>>>(w, u, wb);

    dim3 grid(N_DIM / BN, M_DIM / BM);            // (4, 128)
    gemm_bin_kernel<<<grid, dim3(256), 0, stream>>>(x, wb, out);
}

// Round 4
// 513.025 us; speedup vs baseline: 1.0041x; 1.0041x over previous
//
#include <hip/hip_runtime.h>

// out[B=16384, ONUM=512] = x[B, INUM=4096] @ wB[ONUM, INUM]^T, wB = (u < weight)
// bf16 MFMA path (absmax 8.0 vs threshold 22.56).
// R3/R4: 512-thread blocks (16 waves/CU) + double-buffered LDS pipeline:
//     barrier -> issue k+1 loads -> compute k -> convert/write A(k+1) -> barrier.
//     Both As and Bs XOR-swizzled at stride 64 (no padding) -> 2*32KB = 64KB LDS.
//     (R3 run died to a container/infra failure; identical resubmit.)

#define M_DIM 16384
#define N_DIM 512
#define K_DIM 4096
#define BM 128
#define BN 128
#define BK 64
#define THREADS 512
#define KITERS (K_DIM / BK)

using bf16x8  = __attribute__((ext_vector_type(8))) short;
using ushort8 = __attribute__((ext_vector_type(8))) unsigned short;
using f32x4   = __attribute__((ext_vector_type(4))) float;

typedef __attribute__((address_space(1))) const void glb_cv;
typedef __attribute__((address_space(3))) void lds_v;

__device__ __forceinline__ unsigned short f2bf(float f) {
    union { float f; unsigned int u; } v;
    v.f = f;
    unsigned int r = v.u + 0x7FFFu + ((v.u >> 16) & 1u);   // RNE
    return (unsigned short)(r >> 16);
}

// ---------------- binarize: wB[o,k] = (u < weight) ? 1.0bf16 : 0 ----------------
__global__ __launch_bounds__(256) void binarize_kernel(const float* __restrict__ w,
                                                       const float* __restrict__ u,
                                                       unsigned short* __restrict__ wb) {
    int i = (blockIdx.x * 256 + threadIdx.x) * 4;
    float4 wv = *(const float4*)(w + i);
    float4 uv = *(const float4*)(u + i);
    ushort4 o;
    o.x = (uv.x < wv.x) ? 0x3F80u : 0u;
    o.y = (uv.y < wv.y) ? 0x3F80u : 0u;
    o.z = (uv.z < wv.z) ? 0x3F80u : 0u;
    o.w = (uv.w < wv.w) ? 0x3F80u : 0u;
    *(ushort4*)(wb + i) = o;
}

// ---------------- GEMM: 128x128 tile, BK=64, 8 waves (4x2), 2x4 frags/wave ----------------
__global__ __launch_bounds__(THREADS, 4) void gemm_bin_kernel(const float* __restrict__ x,
                                                              const unsigned short* __restrict__ wb,
                                                              float* __restrict__ out) {
    // 16B-chunk layout: chunk (row r, chunkcol c in 0..7) at index r*8 + (c ^ (r&7))
    __shared__ unsigned short As[2][BM * BK];
    __shared__ unsigned short Bs[2][BN * BK];

    const int t    = threadIdx.x;
    const int lane = t & 63;
    const int wave = t >> 6;
    const int bn   = blockIdx.x;                 // N fastest -> x-tile reuse in cache
    const int bm   = blockIdx.y;

    const int wm = (wave & 3) * 32;              // wave: 32 rows x 64 cols
    const int wn = (wave >> 2) * 64;

    f32x4 acc[2][4] = {};

    // A staging map: thread t -> row t>>2, 16 consecutive floats at col (t&3)*16
    const int ra  = t >> 2;
    const int ca  = (t & 3) * 16;
    const float* xg = x + (size_t)(bm * BM + ra) * K_DIM + ca;
    const unsigned short* wbg = wb + (size_t)(bn * BN) * K_DIM;

    float4 av[4];

    // ---- prologue: stage k=0 into buf 0 ----
#pragma unroll
    for (int i = 0; i < 4; ++i) av[i] = *(const float4*)(xg + i * 4);
#pragma unroll
    for (int c = 0; c < 2; ++c) {
        int e  = c * THREADS + t;
        int rb = e >> 3;
        int gc = (e & 7) ^ (rb & 7);
        __builtin_amdgcn_global_load_lds((glb_cv*)(const void*)(wbg + (size_t)rb * K_DIM + gc * 8),
                                         (lds_v*)(void*)(&Bs[0][e * 8]), 16, 0, 0);
    }
#pragma unroll
    for (int c = 0; c < 2; ++c) {
        ushort8 h;
        float4 v0 = av[c * 2], v1 = av[c * 2 + 1];
        h[0] = f2bf(v0.x); h[1] = f2bf(v0.y); h[2] = f2bf(v0.z); h[3] = f2bf(v0.w);
        h[4] = f2bf(v1.x); h[5] = f2bf(v1.y); h[6] = f2bf(v1.z); h[7] = f2bf(v1.w);
        int cc = (t & 3) * 2 + c;
        *(ushort8*)(&As[0][(ra * 8 + (cc ^ (ra & 7))) * 8]) = h;
    }

    for (int k = 0; k < KITERS; ++k) {
        const int p = k & 1;
        __syncthreads();                          // buf p ready

        if (k + 1 < KITERS) {
            const float* ag = xg + (k + 1) * BK;
#pragma unroll
            for (int i = 0; i < 4; ++i) av[i] = *(const float4*)(ag + i * 4);
#pragma unroll
            for (int c = 0; c < 2; ++c) {
                int e  = c * THREADS + t;
                int rb = e >> 3;
                int gc = (e & 7) ^ (rb & 7);
                __builtin_amdgcn_global_load_lds(
                    (glb_cv*)(const void*)(wbg + (size_t)rb * K_DIM + (k + 1) * BK + gc * 8),
                    (lds_v*)(void*)(&Bs[1 - p][e * 8]), 16, 0, 0);
            }
        }

        // ---- compute from buf p ----
        const unsigned short* Ab = As[p];
        const unsigned short* Bb = Bs[p];
#pragma unroll
        for (int kk = 0; kk < 2; ++kk) {
            const int cc = kk * 4 + (lane >> 4);
            bf16x8 af[2], bfr[4];
#pragma unroll
            for (int i = 0; i < 2; ++i) {
                int r = wm + i * 16 + (lane & 15);
                af[i] = *(const bf16x8*)(Ab + (size_t)(r * 8 + (cc ^ (r & 7))) * 8);
            }
#pragma unroll
            for (int j = 0; j < 4; ++j) {
                int rb = wn + j * 16 + (lane & 15);
                bfr[j] = *(const bf16x8*)(Bb + (size_t)(rb * 8 + (cc ^ (rb & 7))) * 8);
            }
#pragma unroll
            for (int i = 0; i < 2; ++i)
#pragma unroll
                for (int j = 0; j < 4; ++j)
                    acc[i][j] = __builtin_amdgcn_mfma_f32_16x16x32_bf16(af[i], bfr[j], acc[i][j], 0, 0, 0);
        }

        if (k + 1 < KITERS) {                     // convert arrives after compute covered latency
#pragma unroll
            for (int c = 0; c < 2; ++c) {
                ushort8 h;
                float4 v0 = av[c * 2], v1 = av[c * 2 + 1];
                h[0] = f2bf(v0.x); h[1] = f2bf(v0.y); h[2] = f2bf(v0.z); h[3] = f2bf(v0.w);
                h[4] = f2bf(v1.x); h[5] = f2bf(v1.y); h[6] = f2bf(v1.z); h[7] = f2bf(v1.w);
                int cc = (t & 3) * 2 + c;
                *(ushort8*)(&As[1 - p][(ra * 8 + (cc ^ (ra & 7))) * 8]) = h;
            }
        }
    }

    // ---- epilogue: C/D layout col=lane&15, row=(lane>>4)*4+reg ----
    const int col0 = bn * BN + wn + (lane & 15);
    const int row0 = bm * BM + wm + (lane >> 4) * 4;
#pragma unroll
    for (int i = 0; i < 2; ++i)
#pragma unroll
        for (int j = 0; j < 4; ++j)
#pragma unroll
            for (int r = 0; r < 4; ++r)
                out[(size_t)(row0 + i * 16 + r) * N_DIM + (col0 + j * 16)] = acc[i][j][r];
}

extern "C" void kernel_launch(void* const* d_in, const int* in_sizes, int n_in,
                              void* d_out, int out_size, void* d_ws, size_t ws_size,
                              hipStream_t stream) {
    const float* x = (const float*)d_in[0];
    const float* w = (const float*)d_in[1];
    const float* u = (const float*)d_in[2];
    float* out = (float*)d_out;
    unsigned short* wb = (unsigned short*)d_ws;   // 512*4096*2 = 4 MB

    binarize_kernel<<<dim3(N_DIM * K_DIM / 4 / 256), dim3(256), 0, stream>>>(w, u, wb);

    dim3 grid(N_DIM / BN, M_DIM / BM);            // (4, 128)
    gemm_bin_kernel<<<grid, dim3(THREADS), 0, stream>>>(x, wb, out);
}